// Round 1
// 354.372 us; speedup vs baseline: 1.0279x; 1.0279x over previous
//
#include <hip/hip_runtime.h>

// cReLU_percent: x (32,128,112,112) fp32. Per pixel (n,h,w): keep channel
// values >= the 64th-largest across C=128, then ReLU; zero the rest.
//
// R3: keep R2's lane-pair bitonic sort + shfl_xor(1) merge for the threshold,
// but rebuild the epilogue. R2 re-read + stored scalar per channel (64
// dependent 4B L2/L3 round-trips per thread ~ 19K cycles/wave exposed -> the
// 2.3 TB/s plateau). Now: thresholds go through a 512B LDS array + one
// barrier; each thread then owns a fixed pixel-quad and does 16 INDEPENDENT
// float4 re-loads (single vmcnt wait) + 16 nontemporal float4 stores.
// 128 scalar VMEM insts -> 32 vector insts; ~64 round trips -> ~1.
// nt stores keep `out` (write-only) from evicting `x` in L2/L3.

#define CC        128
#define HWSZ      12544     // 112*112
#define PBLK      128       // pixels per block (12544 = 98 * 128)
#define NBLK_PER_N 98

using f32x4 = __attribute__((ext_vector_type(4))) float;

__device__ __forceinline__ void bitonic64(float v[64]) {
  #pragma unroll
  for (int k = 2; k <= 64; k <<= 1) {
    #pragma unroll
    for (int j = k >> 1; j > 0; j >>= 1) {
      #pragma unroll
      for (int i = 0; i < 64; ++i) {
        int l = i ^ j;
        if (l > i) {
          float lo = fminf(v[i], v[l]);
          float hi = fmaxf(v[i], v[l]);
          bool up = ((i & k) == 0);   // compile-time after unroll
          v[i] = up ? lo : hi;
          v[l] = up ? hi : lo;
        }
      }
    }
  }
}

__global__ __launch_bounds__(256) void crelu_pct_kernel(
    const float* __restrict__ x, float* __restrict__ out) {
  __shared__ __align__(16) float thr_lds[PBLK];

  const int tid = threadIdx.x;
  const int n   = blockIdx.x / NBLK_PER_N;
  const int pb  = (blockIdx.x - n * NBLK_PER_N) * PBLK;

  // ---- phase A/B: lane pair (2 lanes per pixel) sorts 64 channels each ----
  const int ql   = tid >> 1;        // local pixel 0..127
  const int half = tid & 1;         // 0: ch 0..63, 1: ch 64..127
  const size_t planeN = (size_t)CC * HWSZ;
  const float* xp = x + (size_t)n * planeN
                      + (size_t)(half << 6) * HWSZ
                      + (size_t)(pb + ql);

  float v[64];
  #pragma unroll
  for (int c = 0; c < 64; ++c) v[c] = xp[(size_t)c * HWSZ];
  bitonic64(v);                     // ascending

  // thr = min_i max(a[i], b[63-i]) via shfl_xor(1); both lanes get same thr
  float thr;
  {
    float mine  = half ? v[63] : v[0];
    float other = __shfl_xor(mine, 1, 64);
    thr = fmaxf(mine, other);
    #pragma unroll
    for (int i = 1; i < 64; ++i) {
      float m = half ? v[63 - i] : v[i];
      float o = __shfl_xor(m, 1, 64);
      thr = fminf(thr, fmaxf(m, o));
    }
  }
  if (!half) thr_lds[ql] = thr;
  __syncthreads();

  // ---- phase D: pixel-major float4 re-read + masked nontemporal store ----
  // thread -> fixed pixel-quad j (pixels pb+4j..pb+4j+3), channels c0+8i.
  const int j  = tid & 31;
  const int c0 = tid >> 5;          // 0..7
  const f32x4 t4 = *reinterpret_cast<const f32x4*>(&thr_lds[j << 2]);
  const size_t rowpix = (size_t)n * planeN + (size_t)pb + (size_t)(j << 2);

  f32x4 w[16];
  #pragma unroll
  for (int i = 0; i < 16; ++i) {
    const int c = (i << 3) + c0;
    w[i] = *reinterpret_cast<const f32x4*>(x + rowpix + (size_t)c * HWSZ);
  }
  #pragma unroll
  for (int i = 0; i < 16; ++i) {
    const int c = (i << 3) + c0;
    f32x4 r;
    #pragma unroll
    for (int e = 0; e < 4; ++e)
      r[e] = (w[i][e] >= t4[e] && w[i][e] > 0.0f) ? w[i][e] : 0.0f;
    __builtin_nontemporal_store(
        r, reinterpret_cast<f32x4*>(out + rowpix + (size_t)c * HWSZ));
  }
}

extern "C" void kernel_launch(void* const* d_in, const int* in_sizes, int n_in,
                              void* d_out, int out_size, void* d_ws, size_t ws_size,
                              hipStream_t stream) {
  const float* x = (const float*)d_in[0];
  float* out = (float*)d_out;
  const int npix = in_sizes[0] / CC;     // 401408
  const int grid = npix / PBLK;          // 3136 exactly
  crelu_pct_kernel<<<grid, 256, 0, stream>>>(x, out);
}